// Round 16
// baseline (23601.227 us; speedup 1.0000x reference)
//
#include <hip/hip_runtime.h>
#include <hip/hip_fp16.h>

// ============================================================================
// 2-layer LSTM with projection (proj_size=128, H=1024, B=64, T=2048)
//
// Round 16 = round 15 (17.0 ms) + three chain cuts:
//  1. VALU-BURNING poll: 128 indep FMAs per poll iteration (asm-sunk).
//     r15's bare spin left VALUBusy at 2.7% (waves stalled in vmcnt) -- the
//     downclock hypothesis was never exercised. Burn overlaps load latency;
//     if DPM throttles on idleness, this holds SCLK up. Tell: VALUBusy.
//  2. DIRECT-FRAGMENT h reads: consumer lanes load h (l1: +h1) straight from
//     MALL into MFMA A-fragment registers (each lane reads its fragment's 8
//     floats per K-slice) -- deletes h_lds/x1_lds bounce AND one barrier
//     from the serial chain. Cost: wx-duplicated reads (2x MALL traffic,
//     fine in latency-bound regime). Out rows written by WG32/wx0 (holds
//     full rows). LDS now s_lds only.
//  3. Zero-slot store moved AFTER the flag store (off critical chain;
//     drained by next step's vm_drain, needed only at t+4; disjoint from
//     step-t adds -- ordering audited).
// Everything else = r12/r15: 32 WGs/layer x 256 thr, register-resident f16
// weights (r7 packing), per-WG flag stores, all-wave poll, l0 x-GEMM
// hoisted pre-poll, atomic-add h-accumulation in 8-deep slot ring, relaxed
// AGENT (sc1) atomics, no cache maintenance, timeout + canary.
// Throttles: l0 step t: own f0>=t, f1>=t-3. l1 step t: f0>=t+1, own f1>=t.
// ============================================================================

typedef _Float16 f16;
typedef _Float16 f16x4 __attribute__((ext_vector_type(4)));
typedef _Float16 f16x8 __attribute__((ext_vector_type(8)));
typedef float f32x4 __attribute__((ext_vector_type(4)));
typedef unsigned long long u64;
struct U128 { u64 lo, hi; };

#define TSTEPS 2048
#define NW 32
#define TIMEOUT_TICKS 200000000ull   // ~2 s at 100 MHz s_memrealtime

// ---- workspace layout (bytes) ----
#define BSW_OFF  0ull
#define BSW_SZ   (64ull*32768ull*2ull)        // gate weights, 4 MiB
#define WHR_OFF  (BSW_OFF + BSW_SZ)
#define WHR_SZ   (64ull*4096ull*2ull)         // proj weights, 512 KiB
#define BIAS_OFF (WHR_OFF + WHR_SZ)
#define BIAS_SZ  (8192ull*4ull)
#define HACC_OFF (BIAS_OFF + BIAS_SZ)
#define HACC_SZ  (2ull*8ull*8192ull*4ull)     // [lyr][slot8][64b x 128p] f32
#define FLAG_OFF (HACC_OFF + HACC_SZ)
#define FLAG_SZ  (512ull)                     // f0[32] @0, f1[32] @128B
#define WS_NEED  (FLAG_OFF + FLAG_SZ)

__device__ __forceinline__ float sigm(float v) {
  float e = __builtin_amdgcn_exp2f(-1.4426950408889634f * v);
  return __builtin_amdgcn_rcpf(1.0f + e);
}
__device__ __forceinline__ float tanh_(float v) {
  float a = fabsf(v);
  float e = __builtin_amdgcn_exp2f(-2.8853900817779268f * a);
  float r = (1.0f - e) * __builtin_amdgcn_rcpf(1.0f + e);
  return copysignf(r, v);
}

// ---- relaxed agent-scope atomic helpers (compile to global_* sc1) --------
__device__ __forceinline__ u64 ald64(const void* p) {
  return __hip_atomic_load((const u64*)p, __ATOMIC_RELAXED, __HIP_MEMORY_SCOPE_AGENT);
}
__device__ __forceinline__ unsigned ald32u(const unsigned* p) {
  return __hip_atomic_load(p, __ATOMIC_RELAXED, __HIP_MEMORY_SCOPE_AGENT);
}
__device__ __forceinline__ void ast32f(float* p, float v) {
  __hip_atomic_store((unsigned*)p, __builtin_bit_cast(unsigned, v),
                     __ATOMIC_RELAXED, __HIP_MEMORY_SCOPE_AGENT);
}
__device__ __forceinline__ void ast32u(unsigned* p, unsigned v) {
  __hip_atomic_store(p, v, __ATOMIC_RELAXED, __HIP_MEMORY_SCOPE_AGENT);
}
__device__ __forceinline__ f32x4 ald_f32x4(const float* p) {
  U128 u; u.lo = ald64(p); u.hi = ald64(p + 2);
  return __builtin_bit_cast(f32x4, u);
}
__device__ __forceinline__ void aadd_f32(float* p, float v) {
  (void)__hip_atomic_fetch_add(p, v, __ATOMIC_RELAXED, __HIP_MEMORY_SCOPE_AGENT);
}
__device__ __forceinline__ void vm_drain() {
  asm volatile("s_waitcnt vmcnt(0)" ::: "memory");
}

// ---------------------------------------------------------------------------
// Setup (round-7 weight packing, proven). Fragment conventions (16x16x32):
//   A-frag: lane l holds A[m=l&15][k=(l>>4)*8+i]
//   B-frag: lane l holds B[k=(l>>4)*8+i][n=l&15]
//   D:      lane l, reg r -> D[m=(l>>4)*4+r][n=l&15]
// ---------------------------------------------------------------------------
__global__ void lstm_setup(
    const float* __restrict__ Wih0, const float* __restrict__ Whh0,
    const float* __restrict__ bih0, const float* __restrict__ bhh0,
    const float* __restrict__ Whr0,
    const float* __restrict__ Wih1, const float* __restrict__ Whh1,
    const float* __restrict__ bih1, const float* __restrict__ bhh1,
    const float* __restrict__ Whr1,
    f16* __restrict__ Bsw, f16* __restrict__ Whrsw, float* __restrict__ bias,
    float* __restrict__ hacc, unsigned* __restrict__ flags)
{
  const int blk = blockIdx.x, tid = threadIdx.x;
  if (blk < 64) {
    const int lyr = blk >> 5, w = blk & 31;
    const float* Whh = lyr ? Whh1 : Whh0;
    const float* Wih = lyr ? Wih1 : Wih0;
    f16* dst = Bsw + (size_t)blk * 32768;
    for (int e = tid; e < 32768; e += 256) {
      int i = e & 7, l = (e >> 3) & 63, ntG = (e >> 9) & 7, ks = e >> 12;
      int k  = ks * 32 + (l >> 4) * 8 + i;
      int rl = ntG * 16 + (l & 15);
      int grow = (rl >> 5) * 1024 + w * 32 + (rl & 31);
      float v = (k < 128) ? Whh[grow * 128 + k] : Wih[grow * 128 + (k - 128)];
      dst[e] = (f16)v;
    }
  } else if (blk < 128) {
    const int q = blk - 64, lyr = q >> 5, w = q & 31;
    const float* Whr = lyr ? Whr1 : Whr0;
    f16* dst = Whrsw + (size_t)q * 4096;
    for (int e = tid; e < 4096; e += 256) {
      int i = e & 7, l = (e >> 3) & 63, pnG = e >> 9;
      int p = pnG * 16 + (l & 15);
      int hg = w * 32 + (l >> 4) * 8 + i;
      dst[e] = (f16)Whr[p * 1024 + hg];
    }
  } else if (blk == 128) {
    for (int e = tid; e < 8192; e += 256) {
      int lyr = e >> 12, j = e & 4095;
      bias[e] = lyr ? (bih1[j] + bhh1[j]) : (bih0[j] + bhh0[j]);
    }
  } else {
    for (int e = tid; e < 2 * 8 * 8192; e += 256) ast32f(hacc + e, 0.f);
    if (tid < 128) ast32u(flags + tid, 0u);
  }
}

// ---------------------------------------------------------------------------
// Main persistent kernel: 64 WGs x 256 thr (4 waves, (wy,wx) 2x2; r7 wave
// mapping: gate M-tiles {wy*2,wy*2+1}, gate N-tiles {ntl*2+wx} (ntl = gate
// type); proj P-tiles {pnl*2+wx}).
// ---------------------------------------------------------------------------
__global__ __launch_bounds__(256, 1) void lstm_main(
    const float* __restrict__ x, float* __restrict__ out,
    const f16* __restrict__ Bsw, const f16* __restrict__ Whrsw,
    const float* __restrict__ bias, float* __restrict__ hacc,
    unsigned* __restrict__ flags)
{
  const int tid = threadIdx.x;
  const int lane = tid & 63, wv = tid >> 6;
  const int wy = wv >> 1, wx = wv & 1;
  const int l15 = lane & 15, lg = lane >> 4;
  const int w = blockIdx.x & 31, lyr = blockIdx.x >> 5;

  const u64 tstart = __builtin_amdgcn_s_memrealtime();
  bool tmo = false;

  __shared__ __align__(16) f16 s_lds[64][40];    // s, row=batch, 32 cols used

  // ---- register-resident weights (r7 packing) ----
  f16x8 bf[8][4];
  {
    const f16* bsl = Bsw + (size_t)(lyr * NW + w) * 32768;
#pragma unroll
    for (int ks = 0; ks < 8; ++ks)
#pragma unroll
      for (int ntl = 0; ntl < 4; ++ntl)
        bf[ks][ntl] = *(const f16x8*)(bsl + (((ks * 8 + (ntl * 2 + wx)) * 64 + lane) * 8));
  }
  f16x8 wf[4];
  {
    const f16* wsl = Whrsw + (size_t)(lyr * NW + w) * 4096;
#pragma unroll
    for (int pnl = 0; pnl < 4; ++pnl)
      wf[pnl] = *(const f16x8*)(wsl + (((pnl * 2 + wx) * 64 + lane) * 8));
  }
  float bias_r[4];
#pragma unroll
  for (int ntl = 0; ntl < 4; ++ntl)
    bias_r[ntl] = bias[lyr * 4096 + ntl * 1024 + w * 32 + wx * 16 + l15];

  float c[2][4] = {{0.f,0.f,0.f,0.f},{0.f,0.f,0.f,0.f}};

  unsigned* f0 = flags;        // [32]
  unsigned* f1 = flags + 32;   // [32]
  unsigned* myf = lyr ? f1 : f0;
  float* myacc = hacc + (size_t)lyr * 8 * 8192;
  float* h1a   = hacc;
  __syncthreads();

  for (int t = 0; t <= TSTEPS; ++t) {
    if (lyr == 0 && t == TSTEPS) break;
    const bool tail = (t == TSTEPS);             // l1 only

    // ---- pre-poll: bias init + (l0) x-part of gate GEMM (K=128..255) ------
    f32x4 acc[2][4];
#pragma unroll
    for (int mtl = 0; mtl < 2; ++mtl)
#pragma unroll
      for (int ntl = 0; ntl < 4; ++ntl) {
        f32x4 b4 = {bias_r[ntl], bias_r[ntl], bias_r[ntl], bias_r[ntl]};
        acc[mtl][ntl] = b4;
      }
    if (lyr == 0) {
#pragma unroll
      for (int mtl = 0; mtl < 2; ++mtl) {
        const float* xp = x + ((size_t)((wy * 2 + mtl) * 16 + l15) * TSTEPS + t) * 128 + lg * 8;
#pragma unroll
        for (int ks2 = 0; ks2 < 4; ++ks2) {
          f32x4 v0 = *(const f32x4*)(xp + ks2 * 32);
          f32x4 v1 = *(const f32x4*)(xp + ks2 * 32 + 4);
          f16x8 hx;
          hx[0]=(f16)v0[0]; hx[1]=(f16)v0[1]; hx[2]=(f16)v0[2]; hx[3]=(f16)v0[3];
          hx[4]=(f16)v1[0]; hx[5]=(f16)v1[1]; hx[6]=(f16)v1[2]; hx[7]=(f16)v1[3];
#pragma unroll
          for (int ntl = 0; ntl < 4; ++ntl)
            acc[mtl][ntl] = __builtin_amdgcn_mfma_f32_16x16x32_f16(hx, bf[4 + ks2][ntl], acc[mtl][ntl], 0, 0, 0);
        }
      }
    }

    // ========== poll: busy-spin + VALU BURN (tests/exploits DPM) ==========
    {
      int itc = 0;
      float b0 = (float)lane, b1 = b0 + 1.f, b2 = b0 + 2.f, b3 = b0 + 3.f;
      for (;;) {
        bool ok = true;
        if (lane < 32) {
          ok = ald32u(myf + lane) >= (unsigned)t;                     // own layer
        } else {
          const int l2 = lane - 32;
          if (lyr == 0) ok = (t < 4) || (ald32u(f1 + l2) >= (unsigned)(t - 3));
          else          ok = tail || (ald32u(f0 + l2) >= (unsigned)(t + 1));
        }
        // 128 FMAs in 4 independent chains -- overlaps the flag-load
        // latency, keeps the VALU issuing (DPM sees activity).
#pragma unroll
        for (int q = 0; q < 32; ++q) {
          b0 = __builtin_fmaf(b0, 1.000001f, 0.5f);
          b1 = __builtin_fmaf(b1, 1.000001f, 0.5f);
          b2 = __builtin_fmaf(b2, 1.000001f, 0.5f);
          b3 = __builtin_fmaf(b3, 1.000001f, 0.5f);
        }
        asm volatile("" : "+v"(b0), "+v"(b1), "+v"(b2), "+v"(b3));  // no DCE
        if (__all(ok)) break;
        if ((++itc & 63) == 0) {
          if ((__builtin_amdgcn_s_memrealtime() - tstart) > TIMEOUT_TICKS) { tmo = true; break; }
        }
      }
    }
    asm volatile("" ::: "memory");

    const float* hp  = myacc + (size_t)((t + 7) & 7) * 8192;   // h_{t-1}
    const float* x1p = h1a + (size_t)(t & 7) * 8192;           // l1: h1_t

    if (tail) {  // l1 only: flush last out rows from h2_{TSTEPS-1}
      if (w == 0 && wx == 0) {
#pragma unroll
        for (int mtl = 0; mtl < 2; ++mtl) {
          const int bm = (wy * 2 + mtl) * 16 + l15;
#pragma unroll
          for (int ks = 0; ks < 4; ++ks) {
            f32x4 lo = ald_f32x4(hp + bm * 128 + ks * 32 + lg * 8);
            f32x4 hi = ald_f32x4(hp + bm * 128 + ks * 32 + lg * 8 + 4);
            float* op = out + (size_t)bm * 8192 + 63 * 128 + ks * 32 + lg * 8;
            *(f32x4*)op = lo;
            *(f32x4*)(op + 4) = hi;
          }
        }
      }
      break;
    }

    // ========== gates: DIRECT-FRAGMENT h reads (no LDS bounce/barrier) =====
#pragma unroll
    for (int mtl = 0; mtl < 2; ++mtl) {
      const int bm = (wy * 2 + mtl) * 16 + l15;
      // h part (K = 0..127)
      f16x8 hf[4];
#pragma unroll
      for (int ks = 0; ks < 4; ++ks) {
        f32x4 lo = ald_f32x4(hp + bm * 128 + ks * 32 + lg * 8);
        f32x4 hi = ald_f32x4(hp + bm * 128 + ks * 32 + lg * 8 + 4);
        if (lyr == 1 && w == 0 && wx == 0 && t >= TSTEPS - 63) {
          float* op = out + (size_t)bm * 8192 + (size_t)(t - 1 - (TSTEPS - 64)) * 128 + ks * 32 + lg * 8;
          *(f32x4*)op = lo;
          *(f32x4*)(op + 4) = hi;
        }
        f16x8 hv;
        hv[0]=(f16)lo[0]; hv[1]=(f16)lo[1]; hv[2]=(f16)lo[2]; hv[3]=(f16)lo[3];
        hv[4]=(f16)hi[0]; hv[5]=(f16)hi[1]; hv[6]=(f16)hi[2]; hv[7]=(f16)hi[3];
        hf[ks] = hv;
      }
#pragma unroll
      for (int ks = 0; ks < 4; ++ks)
#pragma unroll
        for (int ntl = 0; ntl < 4; ++ntl)
          acc[mtl][ntl] = __builtin_amdgcn_mfma_f32_16x16x32_f16(hf[ks], bf[ks][ntl], acc[mtl][ntl], 0, 0, 0);
      if (lyr == 1) {
        // input part (K = 128..255) from l0's accumulator, same frag layout
        f16x8 xf[4];
#pragma unroll
        for (int ks2 = 0; ks2 < 4; ++ks2) {
          f32x4 lo = ald_f32x4(x1p + bm * 128 + ks2 * 32 + lg * 8);
          f32x4 hi = ald_f32x4(x1p + bm * 128 + ks2 * 32 + lg * 8 + 4);
          f16x8 hv;
          hv[0]=(f16)lo[0]; hv[1]=(f16)lo[1]; hv[2]=(f16)lo[2]; hv[3]=(f16)lo[3];
          hv[4]=(f16)hi[0]; hv[5]=(f16)hi[1]; hv[6]=(f16)hi[2]; hv[7]=(f16)hi[3];
          xf[ks2] = hv;
        }
#pragma unroll
        for (int ks2 = 0; ks2 < 4; ++ks2)
#pragma unroll
          for (int ntl = 0; ntl < 4; ++ntl)
            acc[mtl][ntl] = __builtin_amdgcn_mfma_f32_16x16x32_f16(xf[ks2], bf[4 + ks2][ntl], acc[mtl][ntl], 0, 0, 0);
      }
      // elementwise: ntl = gate type (i,f,g,o) for unit wx*16+l15
#pragma unroll
      for (int r = 0; r < 4; ++r) {
        float gi = acc[mtl][0][r], gf = acc[mtl][1][r];
        float gg = acc[mtl][2][r], go = acc[mtl][3][r];
        float cc = sigm(gf) * c[mtl][r] + sigm(gi) * tanh_(gg);
        c[mtl][r] = cc;
        float s = sigm(go) * tanh_(cc);
        s_lds[(wy * 2 + mtl) * 16 + lg * 4 + r][wx * 16 + l15] = (f16)s;
      }
    }
    __syncthreads();

    // ================= proj [64,32]x[32,128] + atomic-add accumulate =======
    {
      float* dst = myacc + (size_t)(t & 7) * 8192;
#pragma unroll
      for (int pml = 0; pml < 2; ++pml) {
        f16x8 ap = *(const f16x8*)(&s_lds[(wy * 2 + pml) * 16 + l15][lg * 8]);
#pragma unroll
        for (int pnl = 0; pnl < 4; ++pnl) {
          f32x4 z = {0.f, 0.f, 0.f, 0.f};
          f32x4 pa = __builtin_amdgcn_mfma_f32_16x16x32_f16(ap, wf[pnl], z, 0, 0, 0);
          const int p = (pnl * 2 + wx) * 16 + l15;
#pragma unroll
          for (int r = 0; r < 4; ++r) {
            const int b = (wy * 2 + pml) * 16 + lg * 4 + r;
            aadd_f32(dst + b * 128 + p, pa[r]);
          }
        }
      }
    }
    vm_drain();        // adds acked at MALL
    __syncthreads();   // all waves drained
    if (tid == 0) ast32u(myf + w, (unsigned)(t + 1));

    // ---- zero our p-slice of slot t+4, AFTER the flag (off the chain).
    // Drained by next step's vm_drain -> visible before flag(t+2); first
    // adds to that slot are at t+4, gated by flags>=t+4 >= t+2.  Readers of
    // the old contents (h[t-4]) finished under the f1>=t-3 / own>=t
    // throttles (same window as r12, zero just lands later = safer).
    {
      const int b = tid >> 2;
      ast32f(myacc + (size_t)((t + 4) & 7) * 8192 + b * 128 + w * 4 + (tid & 3), 0.f);
    }
  }

  if (tmo && tid == 0) out[0] = 12345.0f;  // livelock canary
}

extern "C" void kernel_launch(void* const* d_in, const int* in_sizes, int n_in,
                              void* d_out, int out_size, void* d_ws, size_t ws_size,
                              hipStream_t stream)
{
  const float* x    = (const float*)d_in[0];
  const float* Wih0 = (const float*)d_in[1];
  const float* Whh0 = (const float*)d_in[2];
  const float* bih0 = (const float*)d_in[3];
  const float* bhh0 = (const float*)d_in[4];
  const float* Whr0 = (const float*)d_in[5];
  const float* Wih1 = (const float*)d_in[6];
  const float* Whh1 = (const float*)d_in[7];
  const float* bih1 = (const float*)d_in[8];
  const float* bhh1 = (const float*)d_in[9];
  const float* Whr1 = (const float*)d_in[10];

  if (ws_size < WS_NEED) return;

  char* ws = (char*)d_ws;
  f16*      Bsw   = (f16*)(ws + BSW_OFF);
  f16*      Whrsw = (f16*)(ws + WHR_OFF);
  float*    bias  = (float*)(ws + BIAS_OFF);
  float*    hacc  = (float*)(ws + HACC_OFF);
  unsigned* flags = (unsigned*)(ws + FLAG_OFF);

  lstm_setup<<<130, 256, 0, stream>>>(Wih0, Whh0, bih0, bhh0, Whr0,
                                      Wih1, Whh1, bih1, bhh1, Whr1,
                                      Bsw, Whrsw, bias, hacc, flags);
  lstm_main<<<64, 256, 0, stream>>>(x, (float*)d_out, Bsw, Whrsw, bias,
                                    hacc, flags);
}

// Round 17
// 17483.733 us; speedup vs baseline: 1.3499x; 1.3499x over previous
//
#include <hip/hip_runtime.h>
#include <hip/hip_fp16.h>

// ============================================================================
// 2-layer LSTM with projection (proj_size=128, H=1024, B=64, T=2048)
//
// Round 17 = round 15 (17.0 ms, best) + two isolated chain cuts; r16's
// regression (23.6 ms) unbundled: direct-fragment scattered reads + burn
// dropped, off-chain zero kept.
//  1. DOUBLE-PUMPED poll: two back-to-back flag loads per iteration, checked
//     under separate waitcnts (vmcnt(1)/vmcnt(0) schedulable by compiler).
//     Sampling period ~RT/2 -> discovery latency cut ~0.5 RT.
//  2. Zero-slot store AFTER the flag store (off critical chain; zeros drain
//     at t+1's vm_drain; first foreign adds to slot t+4 are flag-gated
//     behind our t+1 flag -- audited r16/r17).
// Everything else byte-identical to r15: 32 WGs/layer x 256 thr, register-
// resident f16 weights (r7 packing), per-WG flag stores f0[32]/f1[32],
// all-wave busy poll, l0 x-GEMM hoisted pre-poll, coalesced h/h1 read ->
// f16 -> LDS bounce, atomic-add h-accumulation in 8-deep slot ring, relaxed
// AGENT (sc1) atomics, no cache maintenance, timeout + canary.
// Throttles: l0 step t: own f0>=t, f1>=t-3. l1 step t: f0>=t+1, own f1>=t.
// ============================================================================

typedef _Float16 f16;
typedef _Float16 f16x4 __attribute__((ext_vector_type(4)));
typedef _Float16 f16x8 __attribute__((ext_vector_type(8)));
typedef float f32x4 __attribute__((ext_vector_type(4)));
typedef unsigned long long u64;
struct U128 { u64 lo, hi; };

#define TSTEPS 2048
#define NW 32
#define TIMEOUT_TICKS 200000000ull   // ~2 s at 100 MHz s_memrealtime

// ---- workspace layout (bytes) ----
#define BSW_OFF  0ull
#define BSW_SZ   (64ull*32768ull*2ull)        // gate weights, 4 MiB
#define WHR_OFF  (BSW_OFF + BSW_SZ)
#define WHR_SZ   (64ull*4096ull*2ull)         // proj weights, 512 KiB
#define BIAS_OFF (WHR_OFF + WHR_SZ)
#define BIAS_SZ  (8192ull*4ull)
#define HACC_OFF (BIAS_OFF + BIAS_SZ)
#define HACC_SZ  (2ull*8ull*8192ull*4ull)     // [lyr][slot8][64b x 128p] f32
#define FLAG_OFF (HACC_OFF + HACC_SZ)
#define FLAG_SZ  (512ull)                     // f0[32] @0, f1[32] @128B
#define WS_NEED  (FLAG_OFF + FLAG_SZ)

__device__ __forceinline__ float sigm(float v) {
  float e = __builtin_amdgcn_exp2f(-1.4426950408889634f * v);
  return __builtin_amdgcn_rcpf(1.0f + e);
}
__device__ __forceinline__ float tanh_(float v) {
  float a = fabsf(v);
  float e = __builtin_amdgcn_exp2f(-2.8853900817779268f * a);
  float r = (1.0f - e) * __builtin_amdgcn_rcpf(1.0f + e);
  return copysignf(r, v);
}

// ---- relaxed agent-scope atomic helpers (compile to global_* sc1) --------
__device__ __forceinline__ u64 ald64(const void* p) {
  return __hip_atomic_load((const u64*)p, __ATOMIC_RELAXED, __HIP_MEMORY_SCOPE_AGENT);
}
__device__ __forceinline__ unsigned ald32u(const unsigned* p) {
  return __hip_atomic_load(p, __ATOMIC_RELAXED, __HIP_MEMORY_SCOPE_AGENT);
}
__device__ __forceinline__ void ast32f(float* p, float v) {
  __hip_atomic_store((unsigned*)p, __builtin_bit_cast(unsigned, v),
                     __ATOMIC_RELAXED, __HIP_MEMORY_SCOPE_AGENT);
}
__device__ __forceinline__ void ast32u(unsigned* p, unsigned v) {
  __hip_atomic_store(p, v, __ATOMIC_RELAXED, __HIP_MEMORY_SCOPE_AGENT);
}
__device__ __forceinline__ f32x4 ald_f32x4(const float* p) {
  U128 u; u.lo = ald64(p); u.hi = ald64(p + 2);
  return __builtin_bit_cast(f32x4, u);
}
__device__ __forceinline__ void aadd_f32(float* p, float v) {
  (void)__hip_atomic_fetch_add(p, v, __ATOMIC_RELAXED, __HIP_MEMORY_SCOPE_AGENT);
}
__device__ __forceinline__ void vm_drain() {
  asm volatile("s_waitcnt vmcnt(0)" ::: "memory");
}

// ---------------------------------------------------------------------------
// Setup (round-7 weight packing, proven). Fragment conventions (16x16x32):
//   A-frag: lane l holds A[m=l&15][k=(l>>4)*8+i]
//   B-frag: lane l holds B[k=(l>>4)*8+i][n=l&15]
//   D:      lane l, reg r -> D[m=(l>>4)*4+r][n=l&15]
// ---------------------------------------------------------------------------
__global__ void lstm_setup(
    const float* __restrict__ Wih0, const float* __restrict__ Whh0,
    const float* __restrict__ bih0, const float* __restrict__ bhh0,
    const float* __restrict__ Whr0,
    const float* __restrict__ Wih1, const float* __restrict__ Whh1,
    const float* __restrict__ bih1, const float* __restrict__ bhh1,
    const float* __restrict__ Whr1,
    f16* __restrict__ Bsw, f16* __restrict__ Whrsw, float* __restrict__ bias,
    float* __restrict__ hacc, unsigned* __restrict__ flags)
{
  const int blk = blockIdx.x, tid = threadIdx.x;
  if (blk < 64) {
    const int lyr = blk >> 5, w = blk & 31;
    const float* Whh = lyr ? Whh1 : Whh0;
    const float* Wih = lyr ? Wih1 : Wih0;
    f16* dst = Bsw + (size_t)blk * 32768;
    for (int e = tid; e < 32768; e += 256) {
      int i = e & 7, l = (e >> 3) & 63, ntG = (e >> 9) & 7, ks = e >> 12;
      int k  = ks * 32 + (l >> 4) * 8 + i;
      int rl = ntG * 16 + (l & 15);
      int grow = (rl >> 5) * 1024 + w * 32 + (rl & 31);
      float v = (k < 128) ? Whh[grow * 128 + k] : Wih[grow * 128 + (k - 128)];
      dst[e] = (f16)v;
    }
  } else if (blk < 128) {
    const int q = blk - 64, lyr = q >> 5, w = q & 31;
    const float* Whr = lyr ? Whr1 : Whr0;
    f16* dst = Whrsw + (size_t)q * 4096;
    for (int e = tid; e < 4096; e += 256) {
      int i = e & 7, l = (e >> 3) & 63, pnG = e >> 9;
      int p = pnG * 16 + (l & 15);
      int hg = w * 32 + (l >> 4) * 8 + i;
      dst[e] = (f16)Whr[p * 1024 + hg];
    }
  } else if (blk == 128) {
    for (int e = tid; e < 8192; e += 256) {
      int lyr = e >> 12, j = e & 4095;
      bias[e] = lyr ? (bih1[j] + bhh1[j]) : (bih0[j] + bhh0[j]);
    }
  } else {
    for (int e = tid; e < 2 * 8 * 8192; e += 256) ast32f(hacc + e, 0.f);
    if (tid < 128) ast32u(flags + tid, 0u);
  }
}

// ---------------------------------------------------------------------------
// Main persistent kernel: 64 WGs x 256 thr (4 waves, (wy,wx) 2x2; r7 wave
// mapping: gate M-tiles {wy*2,wy*2+1}, gate N-tiles {ntl*2+wx} (ntl = gate
// type); proj P-tiles {pnl*2+wx}).
// ---------------------------------------------------------------------------
__global__ __launch_bounds__(256, 1) void lstm_main(
    const float* __restrict__ x, float* __restrict__ out,
    const f16* __restrict__ Bsw, const f16* __restrict__ Whrsw,
    const float* __restrict__ bias, float* __restrict__ hacc,
    unsigned* __restrict__ flags)
{
  const int tid = threadIdx.x;
  const int lane = tid & 63, wv = tid >> 6;
  const int wy = wv >> 1, wx = wv & 1;
  const int l15 = lane & 15, lg = lane >> 4;
  const int w = blockIdx.x & 31, lyr = blockIdx.x >> 5;

  const u64 tstart = __builtin_amdgcn_s_memrealtime();
  bool tmo = false;

  __shared__ __align__(16) f16 h_lds[64][136];   // h_{t-1}, row=batch, col=p
  __shared__ __align__(16) f16 x1_lds[64][136];  // l1: h1_t
  __shared__ __align__(16) f16 s_lds[64][40];    // s, row=batch, 32 cols used

  // ---- register-resident weights (r7 packing) ----
  f16x8 bf[8][4];
  {
    const f16* bsl = Bsw + (size_t)(lyr * NW + w) * 32768;
#pragma unroll
    for (int ks = 0; ks < 8; ++ks)
#pragma unroll
      for (int ntl = 0; ntl < 4; ++ntl)
        bf[ks][ntl] = *(const f16x8*)(bsl + (((ks * 8 + (ntl * 2 + wx)) * 64 + lane) * 8));
  }
  f16x8 wf[4];
  {
    const f16* wsl = Whrsw + (size_t)(lyr * NW + w) * 4096;
#pragma unroll
    for (int pnl = 0; pnl < 4; ++pnl)
      wf[pnl] = *(const f16x8*)(wsl + (((pnl * 2 + wx) * 64 + lane) * 8));
  }
  float bias_r[4];
#pragma unroll
  for (int ntl = 0; ntl < 4; ++ntl)
    bias_r[ntl] = bias[lyr * 4096 + ntl * 1024 + w * 32 + wx * 16 + l15];

  float c[2][4] = {{0.f,0.f,0.f,0.f},{0.f,0.f,0.f,0.f}};

  unsigned* f0 = flags;        // [32]
  unsigned* f1 = flags + 32;   // [32]
  unsigned* myf = lyr ? f1 : f0;
  float* myacc = hacc + (size_t)lyr * 8 * 8192;
  float* h1a   = hacc;
  __syncthreads();

  for (int t = 0; t <= TSTEPS; ++t) {
    if (lyr == 0 && t == TSTEPS) break;
    const bool tail = (t == TSTEPS);             // l1 only

    // ---- pre-poll: bias init + (l0) x-part of gate GEMM (K=128..255) ------
    f32x4 acc[2][4];
#pragma unroll
    for (int mtl = 0; mtl < 2; ++mtl)
#pragma unroll
      for (int ntl = 0; ntl < 4; ++ntl) {
        f32x4 b4 = {bias_r[ntl], bias_r[ntl], bias_r[ntl], bias_r[ntl]};
        acc[mtl][ntl] = b4;
      }
    if (lyr == 0) {
#pragma unroll
      for (int mtl = 0; mtl < 2; ++mtl) {
        const float* xp = x + ((size_t)((wy * 2 + mtl) * 16 + l15) * TSTEPS + t) * 128 + lg * 8;
#pragma unroll
        for (int ks2 = 0; ks2 < 4; ++ks2) {
          f32x4 v0 = *(const f32x4*)(xp + ks2 * 32);
          f32x4 v1 = *(const f32x4*)(xp + ks2 * 32 + 4);
          f16x8 hx;
          hx[0]=(f16)v0[0]; hx[1]=(f16)v0[1]; hx[2]=(f16)v0[2]; hx[3]=(f16)v0[3];
          hx[4]=(f16)v1[0]; hx[5]=(f16)v1[1]; hx[6]=(f16)v1[2]; hx[7]=(f16)v1[3];
#pragma unroll
          for (int ntl = 0; ntl < 4; ++ntl)
            acc[mtl][ntl] = __builtin_amdgcn_mfma_f32_16x16x32_f16(hx, bf[4 + ks2][ntl], acc[mtl][ntl], 0, 0, 0);
        }
      }
    }

    // ========== poll: DOUBLE-PUMPED busy-spin, all waves independently =====
    // Two loads in flight per iteration, checked under separate waitcnts ->
    // sampling period ~RT/2. Per-lane (ptr, thr) precomputed; thr=0 encodes
    // always-true (t<4 warm-up / tail).
    {
      const unsigned* ptr;
      unsigned thr;
      if (lane < 32) {
        ptr = myf + lane;
        thr = (unsigned)t;
      } else {
        const int l2 = lane - 32;
        if (lyr == 0) { ptr = f1 + l2; thr = (t < 4) ? 0u : (unsigned)(t - 3); }
        else          { ptr = f0 + l2; thr = tail ? 0u : (unsigned)(t + 1); }
      }
      int itc = 0;
      for (;;) {
        unsigned a0 = ald32u(ptr);
        unsigned a1 = ald32u(ptr);
        if (__all(a0 >= thr)) break;
        if (__all(a1 >= thr)) break;
        if ((++itc & 63) == 0) {
          if ((__builtin_amdgcn_s_memrealtime() - tstart) > TIMEOUT_TICKS) { tmo = true; break; }
        }
      }
    }
    asm volatile("" ::: "memory");

    // ================= read: issue ALL loads, then convert =================
    {
      const int b = tid >> 2, pb = (tid & 3) * 32;       // 32 f32 per thread
      const float* hp = myacc + (size_t)((t + 7) & 7) * 8192 + b * 128 + pb;
      f32x4 hv4[8];
#pragma unroll
      for (int k = 0; k < 8; ++k) hv4[k] = ald_f32x4(hp + k * 4);
      f32x4 x1v[8];
      if (lyr == 1 && !tail) {
        const float* xp1 = h1a + (size_t)(t & 7) * 8192 + b * 128 + pb;
#pragma unroll
        for (int k = 0; k < 8; ++k) x1v[k] = ald_f32x4(xp1 + k * 4);
      }
      // out rows from h2_{t-1}; WG w owns p-slice [4w, 4w+4)
      if (lyr == 1 && t >= TSTEPS - 63 && (tid & 3) == (w >> 3))
        *(f32x4*)(out + (size_t)b * 8192 + (t - 1 - (TSTEPS - 64)) * 128 + w * 4) = hv4[w & 7];
#pragma unroll
      for (int k = 0; k < 8; ++k) {
        f16x4 h16;
#pragma unroll
        for (int e = 0; e < 4; ++e) h16[e] = (f16)hv4[k][e];
        *(f16x4*)(&h_lds[b][pb + k * 4]) = h16;
      }
      if (lyr == 1 && !tail) {
#pragma unroll
        for (int k = 0; k < 8; ++k) {
          f16x4 h16;
#pragma unroll
          for (int e = 0; e < 4; ++e) h16[e] = (f16)x1v[k][e];
          *(f16x4*)(&x1_lds[b][pb + k * 4]) = h16;
        }
      }
    }
    if (tail) break;   // uniform for all l1 threads
    __syncthreads();

    // ================= gates: recurrent part (+ l1 input part) =============
#pragma unroll
    for (int mtl = 0; mtl < 2; ++mtl) {
#pragma unroll
      for (int ks = 0; ks < 4; ++ks) {
        f16x8 af = *(const f16x8*)(&h_lds[(wy * 2 + mtl) * 16 + l15][ks * 32 + lg * 8]);
#pragma unroll
        for (int ntl = 0; ntl < 4; ++ntl)
          acc[mtl][ntl] = __builtin_amdgcn_mfma_f32_16x16x32_f16(af, bf[ks][ntl], acc[mtl][ntl], 0, 0, 0);
      }
      if (lyr == 1) {
#pragma unroll
        for (int ks2 = 0; ks2 < 4; ++ks2) {
          f16x8 xf = *(const f16x8*)(&x1_lds[(wy * 2 + mtl) * 16 + l15][ks2 * 32 + lg * 8]);
#pragma unroll
          for (int ntl = 0; ntl < 4; ++ntl)
            acc[mtl][ntl] = __builtin_amdgcn_mfma_f32_16x16x32_f16(xf, bf[4 + ks2][ntl], acc[mtl][ntl], 0, 0, 0);
        }
      }
      // elementwise: ntl = gate type (i,f,g,o) for unit wx*16+l15
#pragma unroll
      for (int r = 0; r < 4; ++r) {
        float gi = acc[mtl][0][r], gf = acc[mtl][1][r];
        float gg = acc[mtl][2][r], go = acc[mtl][3][r];
        float cc = sigm(gf) * c[mtl][r] + sigm(gi) * tanh_(gg);
        c[mtl][r] = cc;
        float s = sigm(go) * tanh_(cc);
        s_lds[(wy * 2 + mtl) * 16 + lg * 4 + r][wx * 16 + l15] = (f16)s;
      }
    }
    __syncthreads();

    // ================= proj [64,32]x[32,128] + atomic-add accumulate =======
    {
      float* dst = myacc + (size_t)(t & 7) * 8192;
#pragma unroll
      for (int pml = 0; pml < 2; ++pml) {
        f16x8 ap = *(const f16x8*)(&s_lds[(wy * 2 + pml) * 16 + l15][lg * 8]);
#pragma unroll
        for (int pnl = 0; pnl < 4; ++pnl) {
          f32x4 z = {0.f, 0.f, 0.f, 0.f};
          f32x4 pa = __builtin_amdgcn_mfma_f32_16x16x32_f16(ap, wf[pnl], z, 0, 0, 0);
          const int p = (pnl * 2 + wx) * 16 + l15;
#pragma unroll
          for (int r = 0; r < 4; ++r) {
            const int b = (wy * 2 + pml) * 16 + lg * 4 + r;
            aadd_f32(dst + b * 128 + p, pa[r]);
          }
        }
      }
    }
    vm_drain();        // adds acked at MALL
    __syncthreads();   // all waves drained
    if (tid == 0) ast32u(myf + w, (unsigned)(t + 1));

    // ---- zero our p-slice of slot t+4, AFTER the flag (off the chain).
    // Zeros drain at step t+1's vm_drain (before flag t+1); first foreign
    // adds to slot t+4 are gated on all flags >= t+4 > t+1 -> zeros visible.
    // Readers of the old contents (h[t-4]) finished under the f1>=t-3 /
    // own>=t throttles (same window as r12/r15).
    {
      const int b = tid >> 2;
      ast32f(myacc + (size_t)((t + 4) & 7) * 8192 + b * 128 + w * 4 + (tid & 3), 0.f);
    }
  }

  if (tmo && tid == 0) out[0] = 12345.0f;  // livelock canary
}

extern "C" void kernel_launch(void* const* d_in, const int* in_sizes, int n_in,
                              void* d_out, int out_size, void* d_ws, size_t ws_size,
                              hipStream_t stream)
{
  const float* x    = (const float*)d_in[0];
  const float* Wih0 = (const float*)d_in[1];
  const float* Whh0 = (const float*)d_in[2];
  const float* bih0 = (const float*)d_in[3];
  const float* bhh0 = (const float*)d_in[4];
  const float* Whr0 = (const float*)d_in[5];
  const float* Wih1 = (const float*)d_in[6];
  const float* Whh1 = (const float*)d_in[7];
  const float* bih1 = (const float*)d_in[8];
  const float* bhh1 = (const float*)d_in[9];
  const float* Whr1 = (const float*)d_in[10];

  if (ws_size < WS_NEED) return;

  char* ws = (char*)d_ws;
  f16*      Bsw   = (f16*)(ws + BSW_OFF);
  f16*      Whrsw = (f16*)(ws + WHR_OFF);
  float*    bias  = (float*)(ws + BIAS_OFF);
  float*    hacc  = (float*)(ws + HACC_OFF);
  unsigned* flags = (unsigned*)(ws + FLAG_OFF);

  lstm_setup<<<130, 256, 0, stream>>>(Wih0, Whh0, bih0, bhh0, Whr0,
                                      Wih1, Whh1, bih1, bhh1, Whr1,
                                      Bsw, Whrsw, bias, hacc, flags);
  lstm_main<<<64, 256, 0, stream>>>(x, (float*)d_out, Bsw, Whrsw, bias,
                                    hacc, flags);
}

// Round 18
// 17033.559 us; speedup vs baseline: 1.3856x; 1.0264x over previous
//
#include <hip/hip_runtime.h>
#include <hip/hip_fp16.h>

// ============================================================================
// 2-layer LSTM with projection (proj_size=128, H=1024, B=64, T=2048)
//
// Round 18 = round 15 RESUBMITTED BYTE-FOR-BYTE (measured best: 17.04 ms,
// absmax 1.2e-4). r17's double-pump+off-chain-zero was null-to-slightly-worse
// (17.48); this locks the session's best kernel back in as the standing one.
//
// Convergence evidence (11 measured configs): 2-hop stores 11.2 us/step;
// 1-hop atomic-add 8.7; half-fan-in 10.8 (worse); flag-stores+all-wave-poll
// 8.4; busy-spin 8.3; +burn/direct-frag 11.5 (worse); double-pump 8.5.
// All sync-topology levers land in the same 8.3-8.7 us/step band with
// VALUBusy ~2.7%, MfmaUtil ~1.4%, HBM ~3.9% -- a cross-XCD producer->
// consumer LATENCY floor (MALL visibility + poll discovery + 32KB read +
// ~1.5 us compute per step), not a throughput roofline.
//
// Design (round 12/13/15 lineage):
//  - 32 WGs/layer x 256 thr, register-resident f16 weights (r7 packing).
//  - Per-WG flag stores f0[32]/f1[32]; all 4 waves busy-spin poll
//    independently (no s_sleep; timeout check every 64 iters, wave-uniform).
//  - l0 x-GEMM hoisted pre-poll; batched h/h1 load issue then convert.
//  - Atomic-add h-accumulation, 8-deep slot ring, zero slot t+4 in the read
//    phase (flag-ordered; audited r8/r9/r11/r12 incl. t<4 warm-up).
//  - Relaxed AGENT (sc1) atomics everywhere; no cache maintenance.
// Throttles: l0 step t: own f0>=t, f1>=t-3. l1 step t: f0>=t+1, own f1>=t.
// ============================================================================

typedef _Float16 f16;
typedef _Float16 f16x4 __attribute__((ext_vector_type(4)));
typedef _Float16 f16x8 __attribute__((ext_vector_type(8)));
typedef float f32x4 __attribute__((ext_vector_type(4)));
typedef unsigned long long u64;
struct U128 { u64 lo, hi; };

#define TSTEPS 2048
#define NW 32
#define TIMEOUT_TICKS 200000000ull   // ~2 s at 100 MHz s_memrealtime

// ---- workspace layout (bytes) ----
#define BSW_OFF  0ull
#define BSW_SZ   (64ull*32768ull*2ull)        // gate weights, 4 MiB
#define WHR_OFF  (BSW_OFF + BSW_SZ)
#define WHR_SZ   (64ull*4096ull*2ull)         // proj weights, 512 KiB
#define BIAS_OFF (WHR_OFF + WHR_SZ)
#define BIAS_SZ  (8192ull*4ull)
#define HACC_OFF (BIAS_OFF + BIAS_SZ)
#define HACC_SZ  (2ull*8ull*8192ull*4ull)     // [lyr][slot8][64b x 128p] f32
#define FLAG_OFF (HACC_OFF + HACC_SZ)
#define FLAG_SZ  (512ull)                     // f0[32] @0, f1[32] @128B
#define WS_NEED  (FLAG_OFF + FLAG_SZ)

__device__ __forceinline__ float sigm(float v) {
  float e = __builtin_amdgcn_exp2f(-1.4426950408889634f * v);
  return __builtin_amdgcn_rcpf(1.0f + e);
}
__device__ __forceinline__ float tanh_(float v) {
  float a = fabsf(v);
  float e = __builtin_amdgcn_exp2f(-2.8853900817779268f * a);
  float r = (1.0f - e) * __builtin_amdgcn_rcpf(1.0f + e);
  return copysignf(r, v);
}

// ---- relaxed agent-scope atomic helpers (compile to global_* sc1) --------
__device__ __forceinline__ u64 ald64(const void* p) {
  return __hip_atomic_load((const u64*)p, __ATOMIC_RELAXED, __HIP_MEMORY_SCOPE_AGENT);
}
__device__ __forceinline__ unsigned ald32u(const unsigned* p) {
  return __hip_atomic_load(p, __ATOMIC_RELAXED, __HIP_MEMORY_SCOPE_AGENT);
}
__device__ __forceinline__ void ast32f(float* p, float v) {
  __hip_atomic_store((unsigned*)p, __builtin_bit_cast(unsigned, v),
                     __ATOMIC_RELAXED, __HIP_MEMORY_SCOPE_AGENT);
}
__device__ __forceinline__ void ast32u(unsigned* p, unsigned v) {
  __hip_atomic_store(p, v, __ATOMIC_RELAXED, __HIP_MEMORY_SCOPE_AGENT);
}
__device__ __forceinline__ f32x4 ald_f32x4(const float* p) {
  U128 u; u.lo = ald64(p); u.hi = ald64(p + 2);
  return __builtin_bit_cast(f32x4, u);
}
__device__ __forceinline__ void aadd_f32(float* p, float v) {
  (void)__hip_atomic_fetch_add(p, v, __ATOMIC_RELAXED, __HIP_MEMORY_SCOPE_AGENT);
}
__device__ __forceinline__ void vm_drain() {
  asm volatile("s_waitcnt vmcnt(0)" ::: "memory");
}

// ---------------------------------------------------------------------------
// Setup (round-7 weight packing, proven). Fragment conventions (16x16x32):
//   A-frag: lane l holds A[m=l&15][k=(l>>4)*8+i]
//   B-frag: lane l holds B[k=(l>>4)*8+i][n=l&15]
//   D:      lane l, reg r -> D[m=(l>>4)*4+r][n=l&15]
// ---------------------------------------------------------------------------
__global__ void lstm_setup(
    const float* __restrict__ Wih0, const float* __restrict__ Whh0,
    const float* __restrict__ bih0, const float* __restrict__ bhh0,
    const float* __restrict__ Whr0,
    const float* __restrict__ Wih1, const float* __restrict__ Whh1,
    const float* __restrict__ bih1, const float* __restrict__ bhh1,
    const float* __restrict__ Whr1,
    f16* __restrict__ Bsw, f16* __restrict__ Whrsw, float* __restrict__ bias,
    float* __restrict__ hacc, unsigned* __restrict__ flags)
{
  const int blk = blockIdx.x, tid = threadIdx.x;
  if (blk < 64) {
    const int lyr = blk >> 5, w = blk & 31;
    const float* Whh = lyr ? Whh1 : Whh0;
    const float* Wih = lyr ? Wih1 : Wih0;
    f16* dst = Bsw + (size_t)blk * 32768;
    for (int e = tid; e < 32768; e += 256) {
      int i = e & 7, l = (e >> 3) & 63, ntG = (e >> 9) & 7, ks = e >> 12;
      int k  = ks * 32 + (l >> 4) * 8 + i;
      int rl = ntG * 16 + (l & 15);
      int grow = (rl >> 5) * 1024 + w * 32 + (rl & 31);
      float v = (k < 128) ? Whh[grow * 128 + k] : Wih[grow * 128 + (k - 128)];
      dst[e] = (f16)v;
    }
  } else if (blk < 128) {
    const int q = blk - 64, lyr = q >> 5, w = q & 31;
    const float* Whr = lyr ? Whr1 : Whr0;
    f16* dst = Whrsw + (size_t)q * 4096;
    for (int e = tid; e < 4096; e += 256) {
      int i = e & 7, l = (e >> 3) & 63, pnG = e >> 9;
      int p = pnG * 16 + (l & 15);
      int hg = w * 32 + (l >> 4) * 8 + i;
      dst[e] = (f16)Whr[p * 1024 + hg];
    }
  } else if (blk == 128) {
    for (int e = tid; e < 8192; e += 256) {
      int lyr = e >> 12, j = e & 4095;
      bias[e] = lyr ? (bih1[j] + bhh1[j]) : (bih0[j] + bhh0[j]);
    }
  } else {
    for (int e = tid; e < 2 * 8 * 8192; e += 256) ast32f(hacc + e, 0.f);
    if (tid < 128) ast32u(flags + tid, 0u);
  }
}

// ---------------------------------------------------------------------------
// Main persistent kernel: 64 WGs x 256 thr (4 waves, (wy,wx) 2x2; r7 wave
// mapping: gate M-tiles {wy*2,wy*2+1}, gate N-tiles {ntl*2+wx} (ntl = gate
// type); proj P-tiles {pnl*2+wx}).
// ---------------------------------------------------------------------------
__global__ __launch_bounds__(256, 1) void lstm_main(
    const float* __restrict__ x, float* __restrict__ out,
    const f16* __restrict__ Bsw, const f16* __restrict__ Whrsw,
    const float* __restrict__ bias, float* __restrict__ hacc,
    unsigned* __restrict__ flags)
{
  const int tid = threadIdx.x;
  const int lane = tid & 63, wv = tid >> 6;
  const int wy = wv >> 1, wx = wv & 1;
  const int l15 = lane & 15, lg = lane >> 4;
  const int w = blockIdx.x & 31, lyr = blockIdx.x >> 5;

  const u64 tstart = __builtin_amdgcn_s_memrealtime();
  bool tmo = false;

  __shared__ __align__(16) f16 h_lds[64][136];   // h_{t-1}, row=batch, col=p
  __shared__ __align__(16) f16 x1_lds[64][136];  // l1: h1_t
  __shared__ __align__(16) f16 s_lds[64][40];    // s, row=batch, 32 cols used

  // ---- register-resident weights (r7 packing) ----
  f16x8 bf[8][4];
  {
    const f16* bsl = Bsw + (size_t)(lyr * NW + w) * 32768;
#pragma unroll
    for (int ks = 0; ks < 8; ++ks)
#pragma unroll
      for (int ntl = 0; ntl < 4; ++ntl)
        bf[ks][ntl] = *(const f16x8*)(bsl + (((ks * 8 + (ntl * 2 + wx)) * 64 + lane) * 8));
  }
  f16x8 wf[4];
  {
    const f16* wsl = Whrsw + (size_t)(lyr * NW + w) * 4096;
#pragma unroll
    for (int pnl = 0; pnl < 4; ++pnl)
      wf[pnl] = *(const f16x8*)(wsl + (((pnl * 2 + wx) * 64 + lane) * 8));
  }
  float bias_r[4];
#pragma unroll
  for (int ntl = 0; ntl < 4; ++ntl)
    bias_r[ntl] = bias[lyr * 4096 + ntl * 1024 + w * 32 + wx * 16 + l15];

  float c[2][4] = {{0.f,0.f,0.f,0.f},{0.f,0.f,0.f,0.f}};

  unsigned* f0 = flags;        // [32]
  unsigned* f1 = flags + 32;   // [32]
  unsigned* myf = lyr ? f1 : f0;
  float* myacc = hacc + (size_t)lyr * 8 * 8192;
  float* h1a   = hacc;
  __syncthreads();

  for (int t = 0; t <= TSTEPS; ++t) {
    if (lyr == 0 && t == TSTEPS) break;
    const bool tail = (t == TSTEPS);             // l1 only

    // ---- pre-poll: bias init + (l0) x-part of gate GEMM (K=128..255) ------
    f32x4 acc[2][4];
#pragma unroll
    for (int mtl = 0; mtl < 2; ++mtl)
#pragma unroll
      for (int ntl = 0; ntl < 4; ++ntl) {
        f32x4 b4 = {bias_r[ntl], bias_r[ntl], bias_r[ntl], bias_r[ntl]};
        acc[mtl][ntl] = b4;
      }
    if (lyr == 0) {
#pragma unroll
      for (int mtl = 0; mtl < 2; ++mtl) {
        const float* xp = x + ((size_t)((wy * 2 + mtl) * 16 + l15) * TSTEPS + t) * 128 + lg * 8;
#pragma unroll
        for (int ks2 = 0; ks2 < 4; ++ks2) {
          f32x4 v0 = *(const f32x4*)(xp + ks2 * 32);
          f32x4 v1 = *(const f32x4*)(xp + ks2 * 32 + 4);
          f16x8 hx;
          hx[0]=(f16)v0[0]; hx[1]=(f16)v0[1]; hx[2]=(f16)v0[2]; hx[3]=(f16)v0[3];
          hx[4]=(f16)v1[0]; hx[5]=(f16)v1[1]; hx[6]=(f16)v1[2]; hx[7]=(f16)v1[3];
#pragma unroll
          for (int ntl = 0; ntl < 4; ++ntl)
            acc[mtl][ntl] = __builtin_amdgcn_mfma_f32_16x16x32_f16(hx, bf[4 + ks2][ntl], acc[mtl][ntl], 0, 0, 0);
        }
      }
    }

    // ========== poll: BUSY-SPIN, all waves independently ==========
    // No s_sleep: sample period = one load RT. Timeout every 64 iters.
    {
      int itc = 0;
      for (;;) {
        bool ok = true;
        if (lane < 32) {
          ok = ald32u(myf + lane) >= (unsigned)t;                     // own layer
        } else {
          const int l2 = lane - 32;
          if (lyr == 0) ok = (t < 4) || (ald32u(f1 + l2) >= (unsigned)(t - 3));
          else          ok = tail || (ald32u(f0 + l2) >= (unsigned)(t + 1));
        }
        if (__all(ok)) break;
        if ((++itc & 63) == 0) {
          if ((__builtin_amdgcn_s_memrealtime() - tstart) > TIMEOUT_TICKS) { tmo = true; break; }
        }
      }
    }
    asm volatile("" ::: "memory");

    // ================= read: issue ALL loads, then convert =================
    {
      const int b = tid >> 2, pb = (tid & 3) * 32;       // 32 f32 per thread
      const float* hp = myacc + (size_t)((t + 7) & 7) * 8192 + b * 128 + pb;
      f32x4 hv4[8];
#pragma unroll
      for (int k = 0; k < 8; ++k) hv4[k] = ald_f32x4(hp + k * 4);
      f32x4 x1v[8];
      if (lyr == 1 && !tail) {
        const float* xp1 = h1a + (size_t)(t & 7) * 8192 + b * 128 + pb;
#pragma unroll
        for (int k = 0; k < 8; ++k) x1v[k] = ald_f32x4(xp1 + k * 4);
      }
      // out rows from h2_{t-1}; WG w owns p-slice [4w, 4w+4)
      if (lyr == 1 && t >= TSTEPS - 63 && (tid & 3) == (w >> 3))
        *(f32x4*)(out + (size_t)b * 8192 + (t - 1 - (TSTEPS - 64)) * 128 + w * 4) = hv4[w & 7];
#pragma unroll
      for (int k = 0; k < 8; ++k) {
        f16x4 h16;
#pragma unroll
        for (int e = 0; e < 4; ++e) h16[e] = (f16)hv4[k][e];
        *(f16x4*)(&h_lds[b][pb + k * 4]) = h16;
      }
      if (lyr == 1 && !tail) {
#pragma unroll
        for (int k = 0; k < 8; ++k) {
          f16x4 h16;
#pragma unroll
          for (int e = 0; e < 4; ++e) h16[e] = (f16)x1v[k][e];
          *(f16x4*)(&x1_lds[b][pb + k * 4]) = h16;
        }
      }
      // zero our p-slice [4w,4w+4) of slot t+4 (holds h[t-4]; reads done
      // under the f1>=t-3 / own>=t throttles -- audited r8/r9/r11/r12)
      if (!tail)
        ast32f(myacc + (size_t)((t + 4) & 7) * 8192 + b * 128 + w * 4 + (tid & 3), 0.f);
    }
    if (tail) break;   // uniform for all l1 threads
    __syncthreads();

    // ================= gates: recurrent part (+ l1 input part) =============
#pragma unroll
    for (int mtl = 0; mtl < 2; ++mtl) {
#pragma unroll
      for (int ks = 0; ks < 4; ++ks) {
        f16x8 af = *(const f16x8*)(&h_lds[(wy * 2 + mtl) * 16 + l15][ks * 32 + lg * 8]);
#pragma unroll
        for (int ntl = 0; ntl < 4; ++ntl)
          acc[mtl][ntl] = __builtin_amdgcn_mfma_f32_16x16x32_f16(af, bf[ks][ntl], acc[mtl][ntl], 0, 0, 0);
      }
      if (lyr == 1) {
#pragma unroll
        for (int ks2 = 0; ks2 < 4; ++ks2) {
          f16x8 xf = *(const f16x8*)(&x1_lds[(wy * 2 + mtl) * 16 + l15][ks2 * 32 + lg * 8]);
#pragma unroll
          for (int ntl = 0; ntl < 4; ++ntl)
            acc[mtl][ntl] = __builtin_amdgcn_mfma_f32_16x16x32_f16(xf, bf[4 + ks2][ntl], acc[mtl][ntl], 0, 0, 0);
        }
      }
      // elementwise: ntl = gate type (i,f,g,o) for unit wx*16+l15
#pragma unroll
      for (int r = 0; r < 4; ++r) {
        float gi = acc[mtl][0][r], gf = acc[mtl][1][r];
        float gg = acc[mtl][2][r], go = acc[mtl][3][r];
        float cc = sigm(gf) * c[mtl][r] + sigm(gi) * tanh_(gg);
        c[mtl][r] = cc;
        float s = sigm(go) * tanh_(cc);
        s_lds[(wy * 2 + mtl) * 16 + lg * 4 + r][wx * 16 + l15] = (f16)s;
      }
    }
    __syncthreads();

    // ================= proj [64,32]x[32,128] + atomic-add accumulate =======
    {
      float* dst = myacc + (size_t)(t & 7) * 8192;
#pragma unroll
      for (int pml = 0; pml < 2; ++pml) {
        f16x8 ap = *(const f16x8*)(&s_lds[(wy * 2 + pml) * 16 + l15][lg * 8]);
#pragma unroll
        for (int pnl = 0; pnl < 4; ++pnl) {
          f32x4 z = {0.f, 0.f, 0.f, 0.f};
          f32x4 pa = __builtin_amdgcn_mfma_f32_16x16x32_f16(ap, wf[pnl], z, 0, 0, 0);
          const int p = (pnl * 2 + wx) * 16 + l15;
#pragma unroll
          for (int r = 0; r < 4; ++r) {
            const int b = (wy * 2 + pml) * 16 + lg * 4 + r;
            aadd_f32(dst + b * 128 + p, pa[r]);
          }
        }
      }
    }
    vm_drain();        // adds + zero stores acked at MALL
    __syncthreads();   // all waves drained
    if (tid == 0) ast32u(myf + w, (unsigned)(t + 1));
  }

  if (tmo && tid == 0) out[0] = 12345.0f;  // livelock canary
}

extern "C" void kernel_launch(void* const* d_in, const int* in_sizes, int n_in,
                              void* d_out, int out_size, void* d_ws, size_t ws_size,
                              hipStream_t stream)
{
  const float* x    = (const float*)d_in[0];
  const float* Wih0 = (const float*)d_in[1];
  const float* Whh0 = (const float*)d_in[2];
  const float* bih0 = (const float*)d_in[3];
  const float* bhh0 = (const float*)d_in[4];
  const float* Whr0 = (const float*)d_in[5];
  const float* Wih1 = (const float*)d_in[6];
  const float* Whh1 = (const float*)d_in[7];
  const float* bih1 = (const float*)d_in[8];
  const float* bhh1 = (const float*)d_in[9];
  const float* Whr1 = (const float*)d_in[10];

  if (ws_size < WS_NEED) return;

  char* ws = (char*)d_ws;
  f16*      Bsw   = (f16*)(ws + BSW_OFF);
  f16*      Whrsw = (f16*)(ws + WHR_OFF);
  float*    bias  = (float*)(ws + BIAS_OFF);
  float*    hacc  = (float*)(ws + HACC_OFF);
  unsigned* flags = (unsigned*)(ws + FLAG_OFF);

  lstm_setup<<<130, 256, 0, stream>>>(Wih0, Whh0, bih0, bhh0, Whr0,
                                      Wih1, Whh1, bih1, bhh1, Whr1,
                                      Bsw, Whrsw, bias, hacc, flags);
  lstm_main<<<64, 256, 0, stream>>>(x, (float*)d_out, Bsw, Whrsw, bias,
                                    hacc, flags);
}